// Round 1
// baseline (384.000 us; speedup 1.0000x reference)
//
#include <hip/hip_runtime.h>
#include <hip/hip_bf16.h>
#include <stdint.h>

// QSCrossAttention: B=8, Nq=1024, Nkv=4096, D=512, fp32 I/O, bf16 MFMA compute.
// Threshold is 2% of max|ref| (measured round 0), so bf16 internals are safe.

typedef __bf16 bf16;
typedef bf16 bf16x8 __attribute__((ext_vector_type(8)));
typedef bf16 bf16x4 __attribute__((ext_vector_type(4)));
typedef float f32x4 __attribute__((ext_vector_type(4)));

#define NB 8
#define NQ 1024
#define NKV 4096
#define DD 512

__device__ __forceinline__ void direct16(const void* g, void* s) {
  __builtin_amdgcn_global_load_lds(
      (const __attribute__((address_space(1))) void*)g,
      (__attribute__((address_space(3))) void*)s, 16, 0, 0);
}

// fp32 -> bf16 bulk convert, 4 elems/thread. n4 = n/4 (all sizes %4 == 0).
__global__ void cvt_kernel(const float* __restrict__ src, bf16* __restrict__ dst, int n4) {
  int i = blockIdx.x * blockDim.x + threadIdx.x;
  if (i < n4) {
    float4 v = ((const float4*)src)[i];
    bf16x4 o;
    o.x = (bf16)v.x; o.y = (bf16)v.y; o.z = (bf16)v.z; o.w = (bf16)v.w;
    ((bf16x4*)dst)[i] = o;
  }
}

// Sniff mask dtype (int32 vs fp32 vs bytes) + zero the softmax denominator.
// mode 0: int32 {0,1}; mode 1: f32 {0,1.0f}; mode 2: bytes.
__global__ void sniff_zero(const unsigned* __restrict__ mask, int* __restrict__ flag,
                           float* __restrict__ denom) {
  __shared__ int s_bad0, s_bad1;
  if (threadIdx.x == 0) { s_bad0 = 0; s_bad1 = 0; }
  __syncthreads();
  int b0 = 0, b1 = 0;
  for (int i = threadIdx.x; i < 8192; i += 256) {  // 32KB: safe for all 3 layouts
    unsigned v = mask[i];
    if (v > 1u) b0 = 1;
    if (v != 0u && v != 0x3F800000u) b1 = 1;
  }
  if (b0) atomicOr(&s_bad0, 1);
  if (b1) atomicOr(&s_bad1, 1);
  for (int i = threadIdx.x; i < NB * NQ; i += 256) denom[i] = 0.f;
  __syncthreads();
  if (threadIdx.x == 0) *flag = (s_bad0 == 0) ? 0 : ((s_bad1 == 0) ? 1 : 2);
}

// C = A[M,K] * B[N,K]^T, 128x128 tile, BK=32, 4 waves each 64x64 (4x4 of 16x16).
// MFMA 16x16x32 bf16. C/D layout: col=lane&15, row=(lane>>4)*4+reg (verified).
// A/B fragment: elem j of lane l = Row[l&15][(l>>4)*8 + j].
// EPI: 0=bf16 store  1=transposed bf16 store (ld=M)  2=exp*mask + atomic rowsum
//      3=divide-by-denom bf16 store  4=fp32 store
template <int EPI>
__global__ void __launch_bounds__(256, 2)
gemm_bt(const bf16* __restrict__ A, const bf16* __restrict__ Bw,
        void* __restrict__ Cp, int N, int K,
        long sA, long sB, long sC,
        const void* __restrict__ mask, const int* __restrict__ flagP,
        float* __restrict__ denom, float scale, int M) {
  __shared__ alignas(16) bf16 As[128 * 32];
  __shared__ alignas(16) bf16 Bs[128 * 32];
  const int tid = threadIdx.x;
  const int wave = tid >> 6, lane = tid & 63;
  const int l15 = lane & 15, l4 = lane >> 4;
  const int wm = (wave >> 1) * 64, wn = (wave & 1) * 64;
  const int b = blockIdx.z;

  const bf16* Ab = A + (long)b * sA + (long)(blockIdx.y * 128) * K;
  const bf16* Bb = Bw + (long)b * sB + (long)(blockIdx.x * 128) * K;

  // staging: each wave fills two 1KB chunks of As and Bs (base + lane*16B)
  const int c0 = wave * 2, c1 = wave * 2 + 1;
  const int srow = lane >> 2;
  const int scol = (lane & 3) * 8;
  const bf16* ag0 = Ab + (long)(c0 * 16 + srow) * K + scol;
  const bf16* ag1 = Ab + (long)(c1 * 16 + srow) * K + scol;
  const bf16* bg0 = Bb + (long)(c0 * 16 + srow) * K + scol;
  const bf16* bg1 = Bb + (long)(c1 * 16 + srow) * K + scol;
  bf16* al0 = As + c0 * 512 + lane * 8;
  bf16* al1 = As + c1 * 512 + lane * 8;
  bf16* bl0 = Bs + c0 * 512 + lane * 8;
  bf16* bl1 = Bs + c1 * 512 + lane * 8;

  f32x4 acc[4][4] = {};

  for (int kt = 0; kt < K; kt += 32) {
    __syncthreads();  // protect LDS from previous iteration's readers
    direct16(ag0, al0);
    direct16(ag1, al1);
    direct16(bg0, bl0);
    direct16(bg1, bl1);
    ag0 += 32; ag1 += 32; bg0 += 32; bg1 += 32;
    __syncthreads();  // drains vmcnt before barrier (compiler-inserted)
    bf16x8 af[4], bfr[4];
#pragma unroll
    for (int t = 0; t < 4; ++t)
      af[t] = *(const bf16x8*)(As + (wm + t * 16 + l15) * 32 + l4 * 8);
#pragma unroll
    for (int t = 0; t < 4; ++t)
      bfr[t] = *(const bf16x8*)(Bs + (wn + t * 16 + l15) * 32 + l4 * 8);
#pragma unroll
    for (int mt = 0; mt < 4; ++mt)
#pragma unroll
      for (int nt = 0; nt < 4; ++nt)
        acc[mt][nt] = __builtin_amdgcn_mfma_f32_16x16x32_bf16(af[mt], bfr[nt],
                                                              acc[mt][nt], 0, 0, 0);
  }

  const int rowBase = blockIdx.y * 128 + wm;
  const int colBase = blockIdx.x * 128 + wn;

  if constexpr (EPI == 0) {
    bf16* C = (bf16*)Cp + (long)b * sC;
#pragma unroll
    for (int mt = 0; mt < 4; ++mt)
#pragma unroll
      for (int nt = 0; nt < 4; ++nt)
#pragma unroll
        for (int r = 0; r < 4; ++r)
          C[(long)(rowBase + mt * 16 + l4 * 4 + r) * N + colBase + nt * 16 + l15] =
              (bf16)acc[mt][nt][r];
  } else if constexpr (EPI == 1) {
    // store C^T (ld = M): the 4 acc regs are 4 consecutive rows -> one 8B store
    bf16* C = (bf16*)Cp + (long)b * sC;
#pragma unroll
    for (int mt = 0; mt < 4; ++mt)
#pragma unroll
      for (int nt = 0; nt < 4; ++nt) {
        bf16x4 o;
        o.x = (bf16)acc[mt][nt][0]; o.y = (bf16)acc[mt][nt][1];
        o.z = (bf16)acc[mt][nt][2]; o.w = (bf16)acc[mt][nt][3];
        long addr = (long)(colBase + nt * 16 + l15) * M + rowBase + mt * 16 + l4 * 4;
        *(bf16x4*)(C + addr) = o;
      }
  } else if constexpr (EPI == 2) {
    // P = keep ? exp(s*scale) : 0 ; store bf16 P ; atomic row-sum into denom.
    // No max-subtraction: |logit| <= ~7.5 worst case, exp fits fp32 easily,
    // masked entries are exactly 0 (matches reference exp(s-10000) -> 0).
    bf16* C = (bf16*)Cp + (long)b * sC;
    const int mode = *flagP;
    float rs[4][4];
#pragma unroll
    for (int mt = 0; mt < 4; ++mt)
#pragma unroll
      for (int r = 0; r < 4; ++r) rs[mt][r] = 0.f;
#pragma unroll
    for (int nt = 0; nt < 4; ++nt) {
      const int col = colBase + nt * 16 + l15;
      bool keep;
      if (mode == 0)      keep = ((const int*)mask)[b * NKV + col] != 0;
      else if (mode == 1) keep = ((const float*)mask)[b * NKV + col] != 0.f;
      else                keep = ((const unsigned char*)mask)[b * NKV + col] != 0;
#pragma unroll
      for (int mt = 0; mt < 4; ++mt)
#pragma unroll
        for (int r = 0; r < 4; ++r) {
          float p = keep ? __expf(acc[mt][nt][r] * scale) : 0.f;
          rs[mt][r] += p;
          C[(long)(rowBase + mt * 16 + l4 * 4 + r) * N + col] = (bf16)p;
        }
    }
#pragma unroll
    for (int mt = 0; mt < 4; ++mt)
#pragma unroll
      for (int r = 0; r < 4; ++r) {
        float v = rs[mt][r];
        v += __shfl_xor(v, 1, 64);
        v += __shfl_xor(v, 2, 64);
        v += __shfl_xor(v, 4, 64);
        v += __shfl_xor(v, 8, 64);
        if (l15 == 0)
          atomicAdd(&denom[b * M + rowBase + mt * 16 + l4 * 4 + r], v);
      }
  } else if constexpr (EPI == 3) {
    bf16* C = (bf16*)Cp + (long)b * sC;
#pragma unroll
    for (int mt = 0; mt < 4; ++mt)
#pragma unroll
      for (int r = 0; r < 4; ++r) {
        const float inv = 1.0f / denom[b * M + rowBase + mt * 16 + l4 * 4 + r];
#pragma unroll
        for (int nt = 0; nt < 4; ++nt)
          C[(long)(rowBase + mt * 16 + l4 * 4 + r) * N + colBase + nt * 16 + l15] =
              (bf16)(acc[mt][nt][r] * inv);
      }
  } else {  // EPI == 4: fp32 store
    float* C = (float*)Cp + (long)b * sC;
#pragma unroll
    for (int mt = 0; mt < 4; ++mt)
#pragma unroll
      for (int nt = 0; nt < 4; ++nt)
#pragma unroll
        for (int r = 0; r < 4; ++r)
          C[(long)(rowBase + mt * 16 + l4 * 4 + r) * N + colBase + nt * 16 + l15] =
              acc[mt][nt][r];
  }
}

extern "C" void kernel_launch(void* const* d_in, const int* in_sizes, int n_in,
                              void* d_out, int out_size, void* d_ws, size_t ws_size,
                              hipStream_t stream) {
  const float* proto = (const float*)d_in[0];
  const float* qx    = (const float*)d_in[1];
  const void*  mask  = d_in[2];
  const float* Wq    = (const float*)d_in[3];
  const float* Wk    = (const float*)d_in[4];
  const float* Wv    = (const float*)d_in[5];
  const float* Wproj = (const float*)d_in[6];
  float* out = (float*)d_out;

  char* w = (char*)d_ws;
  int*   flag  = (int*)w;                 // 4B
  float* denom = (float*)(w + 4096);      // 8*1024 f32 = 32KB
  size_t off = 65536;
  bf16* Wq_b = (bf16*)(w + off); off += (size_t)DD * DD * 2;
  bf16* Wk_b = (bf16*)(w + off); off += (size_t)DD * DD * 2;
  bf16* Wv_b = (bf16*)(w + off); off += (size_t)DD * DD * 2;
  bf16* Wp_b = (bf16*)(w + off); off += (size_t)DD * DD * 2;
  bf16* q_b  = (bf16*)(w + off); off += (size_t)NB * NQ * DD * 2;   // 8MB
  bf16* k_b  = (bf16*)(w + off); off += (size_t)NB * NKV * DD * 2;  // 32MB
  bf16* vT_b = (bf16*)(w + off); off += (size_t)NB * NKV * DD * 2;  // 32MB (vT: [b][e][m])
  bf16* x_b  = (bf16*)(w + off); off += (size_t)NB * NQ * DD * 2;   // 8MB
  size_t off_pp = off;  // proto_b/qx_b live here; P overlaps them (dead by S)
  bf16* proto_b = (bf16*)(w + off); off += (size_t)NB * NQ * DD * 2;
  bf16* qx_b    = (bf16*)(w + off);
  bf16* P       = (bf16*)(w + off_pp);    // 8*1024*4096 bf16 = 64MB

  sniff_zero<<<1, 256, 0, stream>>>((const unsigned*)mask, flag, denom);

  cvt_kernel<<<NB * NQ * DD / 4 / 256, 256, 0, stream>>>(proto, proto_b, NB * NQ * DD / 4);
  cvt_kernel<<<NB * NKV * DD / 4 / 256, 256, 0, stream>>>(qx, qx_b, NB * NKV * DD / 4);
  cvt_kernel<<<DD * DD / 4 / 256, 256, 0, stream>>>(Wq, Wq_b, DD * DD / 4);
  cvt_kernel<<<DD * DD / 4 / 256, 256, 0, stream>>>(Wk, Wk_b, DD * DD / 4);
  cvt_kernel<<<DD * DD / 4 / 256, 256, 0, stream>>>(Wv, Wv_b, DD * DD / 4);
  cvt_kernel<<<DD * DD / 4 / 256, 256, 0, stream>>>(Wproj, Wp_b, DD * DD / 4);

  const float scale = 0.04419417382415922f;  // 512^-0.5

  // q = proto @ Wq^T   [1024x512] per batch
  gemm_bt<0><<<dim3(DD / 128, NQ / 128, NB), 256, 0, stream>>>(
      proto_b, Wq_b, q_b, DD, DD, (long)NQ * DD, 0L, (long)NQ * DD,
      nullptr, nullptr, nullptr, 0.f, NQ);
  // k = qx @ Wk^T      [4096x512]
  gemm_bt<0><<<dim3(DD / 128, NKV / 128, NB), 256, 0, stream>>>(
      qx_b, Wk_b, k_b, DD, DD, (long)NKV * DD, 0L, (long)NKV * DD,
      nullptr, nullptr, nullptr, 0.f, NKV);
  // vT = (qx @ Wv^T)^T [512x4096]
  gemm_bt<1><<<dim3(DD / 128, NKV / 128, NB), 256, 0, stream>>>(
      qx_b, Wv_b, vT_b, DD, DD, (long)NKV * DD, 0L, (long)DD * NKV,
      nullptr, nullptr, nullptr, 0.f, NKV);
  // P = exp(scale * q @ k^T) * mask   [1024x4096]; denom += row sums
  gemm_bt<2><<<dim3(NKV / 128, NQ / 128, NB), 256, 0, stream>>>(
      q_b, k_b, P, NKV, DD, (long)NQ * DD, (long)NKV * DD, (long)NQ * NKV,
      mask, flag, denom, scale, NQ);
  // x = (P @ vT^T) / denom   [1024x512]
  gemm_bt<3><<<dim3(DD / 128, NQ / 128, NB), 256, 0, stream>>>(
      P, vT_b, x_b, DD, NKV, (long)NQ * NKV, (long)DD * NKV, (long)NQ * DD,
      nullptr, nullptr, denom, 0.f, NQ);
  // out = x @ Wproj^T  fp32  [1024x512]
  gemm_bt<4><<<dim3(DD / 128, NQ / 128, NB), 256, 0, stream>>>(
      x_b, Wp_b, out, DD, DD, (long)NQ * DD, 0L, (long)NQ * DD,
      nullptr, nullptr, nullptr, 0.f, NQ);
}

// Round 2
// 368.788 us; speedup vs baseline: 1.0412x; 1.0412x over previous
//
#include <hip/hip_runtime.h>
#include <hip/hip_bf16.h>
#include <stdint.h>

// QSCrossAttention: B=8, Nq=1024, Nkv=4096, D=512, fp32 I/O, bf16 MFMA compute.
// R2: PV split-K 2-way (256->512 blocks; R1 showed PV latency-bound at 1 blk/CU),
//     fused k+v projection (one GEMM, N=1024, dual epilogue), merged weight cvt.

typedef __bf16 bf16;
typedef bf16 bf16x8 __attribute__((ext_vector_type(8)));
typedef bf16 bf16x4 __attribute__((ext_vector_type(4)));
typedef float f32x4 __attribute__((ext_vector_type(4)));

#define NB 8
#define NQ 1024
#define NKV 4096
#define DD 512

__device__ __forceinline__ void direct16(const void* g, void* s) {
  __builtin_amdgcn_global_load_lds(
      (const __attribute__((address_space(1))) void*)g,
      (__attribute__((address_space(3))) void*)s, 16, 0, 0);
}

// fp32 -> bf16 bulk convert, 4 elems/thread.
__global__ void cvt_kernel(const float* __restrict__ src, bf16* __restrict__ dst, int n4) {
  int i = blockIdx.x * blockDim.x + threadIdx.x;
  if (i < n4) {
    float4 v = ((const float4*)src)[i];
    bf16x4 o;
    o.x = (bf16)v.x; o.y = (bf16)v.y; o.z = (bf16)v.z; o.w = (bf16)v.w;
    ((bf16x4*)dst)[i] = o;
  }
}

// Convert all 4 weight matrices in one launch. Wk+Wv go contiguously into Wkv.
__global__ void cvt_weights(const float* __restrict__ Wq, const float* __restrict__ Wk,
                            const float* __restrict__ Wv, const float* __restrict__ Wp,
                            bf16* __restrict__ Wq_b, bf16* __restrict__ Wkv_b,
                            bf16* __restrict__ Wp_b) {
  int i = blockIdx.x * blockDim.x + threadIdx.x;  // 4 * 65536 f4-elems
  int w = i >> 16, r = i & 65535;
  const float* src = (w == 0) ? Wq : (w == 1) ? Wk : (w == 2) ? Wv : Wp;
  bf16x4* dst = (w == 0) ? (bf16x4*)Wq_b
              : (w == 3) ? (bf16x4*)Wp_b
                         : (bf16x4*)Wkv_b + (w == 2 ? 65536 : 0);
  float4 v = ((const float4*)src)[r];
  bf16x4 o;
  o.x = (bf16)v.x; o.y = (bf16)v.y; o.z = (bf16)v.z; o.w = (bf16)v.w;
  dst[r] = o;
}

// Sniff mask dtype (int32 vs fp32 vs bytes) + zero the softmax denominator.
__global__ void sniff_zero(const unsigned* __restrict__ mask, int* __restrict__ flag,
                           float* __restrict__ denom) {
  __shared__ int s_bad0, s_bad1;
  if (threadIdx.x == 0) { s_bad0 = 0; s_bad1 = 0; }
  __syncthreads();
  int b0 = 0, b1 = 0;
  for (int i = threadIdx.x; i < 8192; i += 256) {
    unsigned v = mask[i];
    if (v > 1u) b0 = 1;
    if (v != 0u && v != 0x3F800000u) b1 = 1;
  }
  if (b0) atomicOr(&s_bad0, 1);
  if (b1) atomicOr(&s_bad1, 1);
  for (int i = threadIdx.x; i < NB * NQ; i += 256) denom[i] = 0.f;
  __syncthreads();
  if (threadIdx.x == 0) *flag = (s_bad0 == 0) ? 0 : ((s_bad1 == 0) ? 1 : 2);
}

// x = bf16((p0 + p1) / denom[row]) — split-K reduce + softmax divide.
__global__ void reduce_pv(const float4* __restrict__ p0, const float4* __restrict__ p1,
                          const float* __restrict__ denom, bf16x4* __restrict__ x, int n4) {
  int i = blockIdx.x * blockDim.x + threadIdx.x;
  if (i < n4) {
    float4 a = p0[i], c = p1[i];
    const float inv = 1.0f / denom[i >> 7];  // 512/4 = 128 f4-elems per row
    bf16x4 o;
    o.x = (bf16)((a.x + c.x) * inv); o.y = (bf16)((a.y + c.y) * inv);
    o.z = (bf16)((a.z + c.z) * inv); o.w = (bf16)((a.w + c.w) * inv);
    x[i] = o;
  }
}

// C = A[M,K] * B[N,K]^T, 128x128 tile, BK=32, 4 waves each 64x64 (4x4 of 16x16).
// blockIdx.z = chunk*8 + b (split-K); both A and B advance by chunk*kOff along K.
// EPI: 0=bf16 store  2=exp*mask + atomic rowsum  4=fp32 store (z-indexed)
//      5=kv dual epilogue (n<512 -> k row-major; n>=512 -> vT transposed)
template <int EPI>
__global__ void __launch_bounds__(256, 2)
gemm_bt(const bf16* __restrict__ A, const bf16* __restrict__ Bw,
        void* __restrict__ Cp, void* __restrict__ Cp2,
        int N, int Klen, int Kstride, long kOff,
        long sA, long sB, long sC,
        const void* __restrict__ mask, const int* __restrict__ flagP,
        float* __restrict__ denom, float scale, int M) {
  __shared__ alignas(16) bf16 As[128 * 32];
  __shared__ alignas(16) bf16 Bs[128 * 32];
  const int tid = threadIdx.x;
  const int wave = tid >> 6, lane = tid & 63;
  const int l15 = lane & 15, l4 = lane >> 4;
  const int wm = (wave >> 1) * 64, wn = (wave & 1) * 64;
  const int b = blockIdx.z & 7;
  const int chunk = blockIdx.z >> 3;

  const bf16* Ab = A + (long)b * sA + chunk * kOff + (long)(blockIdx.y * 128) * Kstride;
  const bf16* Bb = Bw + (long)b * sB + chunk * kOff + (long)(blockIdx.x * 128) * Kstride;

  const int c0 = wave * 2, c1 = wave * 2 + 1;
  const int srow = lane >> 2;
  const int scol = (lane & 3) * 8;
  const bf16* ag0 = Ab + (long)(c0 * 16 + srow) * Kstride + scol;
  const bf16* ag1 = Ab + (long)(c1 * 16 + srow) * Kstride + scol;
  const bf16* bg0 = Bb + (long)(c0 * 16 + srow) * Kstride + scol;
  const bf16* bg1 = Bb + (long)(c1 * 16 + srow) * Kstride + scol;
  bf16* al0 = As + c0 * 512 + lane * 8;
  bf16* al1 = As + c1 * 512 + lane * 8;
  bf16* bl0 = Bs + c0 * 512 + lane * 8;
  bf16* bl1 = Bs + c1 * 512 + lane * 8;

  f32x4 acc[4][4] = {};

  for (int kt = 0; kt < Klen; kt += 32) {
    __syncthreads();
    direct16(ag0, al0);
    direct16(ag1, al1);
    direct16(bg0, bl0);
    direct16(bg1, bl1);
    ag0 += 32; ag1 += 32; bg0 += 32; bg1 += 32;
    __syncthreads();
    bf16x8 af[4], bfr[4];
#pragma unroll
    for (int t = 0; t < 4; ++t)
      af[t] = *(const bf16x8*)(As + (wm + t * 16 + l15) * 32 + l4 * 8);
#pragma unroll
    for (int t = 0; t < 4; ++t)
      bfr[t] = *(const bf16x8*)(Bs + (wn + t * 16 + l15) * 32 + l4 * 8);
#pragma unroll
    for (int mt = 0; mt < 4; ++mt)
#pragma unroll
      for (int nt = 0; nt < 4; ++nt)
        acc[mt][nt] = __builtin_amdgcn_mfma_f32_16x16x32_bf16(af[mt], bfr[nt],
                                                              acc[mt][nt], 0, 0, 0);
  }

  const int rowBase = blockIdx.y * 128 + wm;
  const int colBase = blockIdx.x * 128 + wn;

  if constexpr (EPI == 0) {
    bf16* C = (bf16*)Cp + (long)b * sC;
#pragma unroll
    for (int mt = 0; mt < 4; ++mt)
#pragma unroll
      for (int nt = 0; nt < 4; ++nt)
#pragma unroll
        for (int r = 0; r < 4; ++r)
          C[(long)(rowBase + mt * 16 + l4 * 4 + r) * N + colBase + nt * 16 + l15] =
              (bf16)acc[mt][nt][r];
  } else if constexpr (EPI == 2) {
    // P = keep ? exp(s*scale) : 0 ; bf16 store ; atomic row-sum into denom.
    bf16* C = (bf16*)Cp + (long)b * sC;
    const int mode = *flagP;
    float rs[4][4];
#pragma unroll
    for (int mt = 0; mt < 4; ++mt)
#pragma unroll
      for (int r = 0; r < 4; ++r) rs[mt][r] = 0.f;
#pragma unroll
    for (int nt = 0; nt < 4; ++nt) {
      const int col = colBase + nt * 16 + l15;
      bool keep;
      if (mode == 0)      keep = ((const int*)mask)[b * NKV + col] != 0;
      else if (mode == 1) keep = ((const float*)mask)[b * NKV + col] != 0.f;
      else                keep = ((const unsigned char*)mask)[b * NKV + col] != 0;
#pragma unroll
      for (int mt = 0; mt < 4; ++mt)
#pragma unroll
        for (int r = 0; r < 4; ++r) {
          float p = keep ? __expf(acc[mt][nt][r] * scale) : 0.f;
          rs[mt][r] += p;
          C[(long)(rowBase + mt * 16 + l4 * 4 + r) * N + col] = (bf16)p;
        }
    }
#pragma unroll
    for (int mt = 0; mt < 4; ++mt)
#pragma unroll
      for (int r = 0; r < 4; ++r) {
        float v = rs[mt][r];
        v += __shfl_xor(v, 1, 64);
        v += __shfl_xor(v, 2, 64);
        v += __shfl_xor(v, 4, 64);
        v += __shfl_xor(v, 8, 64);
        if (l15 == 0)
          atomicAdd(&denom[b * M + rowBase + mt * 16 + l4 * 4 + r], v);
      }
  } else if constexpr (EPI == 4) {
    // fp32 store; z-indexed so split-K chunks land in consecutive partial slabs
    float* C = (float*)Cp + (long)blockIdx.z * sC;
#pragma unroll
    for (int mt = 0; mt < 4; ++mt)
#pragma unroll
      for (int nt = 0; nt < 4; ++nt)
#pragma unroll
        for (int r = 0; r < 4; ++r)
          C[(long)(rowBase + mt * 16 + l4 * 4 + r) * N + colBase + nt * 16 + l15] =
              acc[mt][nt][r];
  } else {  // EPI == 5: fused kv epilogue. rows flattened over [B][Nkv].
    if (colBase < 512) {
      bf16* C = (bf16*)Cp;  // k: [B*Nkv][512] row-major == flat rows
#pragma unroll
      for (int mt = 0; mt < 4; ++mt)
#pragma unroll
        for (int nt = 0; nt < 4; ++nt)
#pragma unroll
          for (int r = 0; r < 4; ++r)
            C[(long)(rowBase + mt * 16 + l4 * 4 + r) * 512 + colBase + nt * 16 + l15] =
                (bf16)acc[mt][nt][r];
    } else {
      bf16* C = (bf16*)Cp2;  // vT: [B][512][Nkv]
#pragma unroll
      for (int mt = 0; mt < 4; ++mt) {
        const int gm = rowBase + mt * 16 + l4 * 4;  // 4 consecutive flat rows, same batch
        const int bb = gm >> 12, mloc = gm & 4095;
#pragma unroll
        for (int nt = 0; nt < 4; ++nt) {
          const int col = colBase + nt * 16 + l15 - 512;
          bf16x4 o;
          o.x = (bf16)acc[mt][nt][0]; o.y = (bf16)acc[mt][nt][1];
          o.z = (bf16)acc[mt][nt][2]; o.w = (bf16)acc[mt][nt][3];
          *(bf16x4*)(C + (long)bb * DD * NKV + (long)col * NKV + mloc) = o;
        }
      }
    }
  }
}

extern "C" void kernel_launch(void* const* d_in, const int* in_sizes, int n_in,
                              void* d_out, int out_size, void* d_ws, size_t ws_size,
                              hipStream_t stream) {
  const float* proto = (const float*)d_in[0];
  const float* qx    = (const float*)d_in[1];
  const void*  mask  = d_in[2];
  const float* Wq    = (const float*)d_in[3];
  const float* Wk    = (const float*)d_in[4];
  const float* Wv    = (const float*)d_in[5];
  const float* Wproj = (const float*)d_in[6];
  float* out = (float*)d_out;

  char* w = (char*)d_ws;
  int*   flag  = (int*)w;
  float* denom = (float*)(w + 4096);      // 8192 f32
  size_t off = 65536;
  bf16* Wq_b  = (bf16*)(w + off); off += (size_t)DD * DD * 2;
  bf16* Wkv_b = (bf16*)(w + off); off += (size_t)DD * DD * 4;      // [1024][512]
  bf16* Wp_b  = (bf16*)(w + off); off += (size_t)DD * DD * 2;
  bf16* q_b   = (bf16*)(w + off); off += (size_t)NB * NQ * DD * 2;   // 8MB
  bf16* k_b   = (bf16*)(w + off); off += (size_t)NB * NKV * DD * 2;  // 32MB
  float* part = (float*)k_b;  // PV fp32 partials [2][8][1024][512] = 32MB; k dead by then
  bf16* vT_b  = (bf16*)(w + off); off += (size_t)NB * NKV * DD * 2;  // 32MB
  bf16* x_b   = (bf16*)(w + off); off += (size_t)NB * NQ * DD * 2;   // 8MB
  size_t off_pp = off;  // proto_b/qx_b live here; P overlaps them (dead by S)
  bf16* proto_b = (bf16*)(w + off); off += (size_t)NB * NQ * DD * 2;
  bf16* qx_b    = (bf16*)(w + off);
  bf16* P       = (bf16*)(w + off_pp);    // 64MB

  sniff_zero<<<1, 256, 0, stream>>>((const unsigned*)mask, flag, denom);

  cvt_kernel<<<NB * NQ * DD / 4 / 256, 256, 0, stream>>>(proto, proto_b, NB * NQ * DD / 4);
  cvt_kernel<<<NB * NKV * DD / 4 / 256, 256, 0, stream>>>(qx, qx_b, NB * NKV * DD / 4);
  cvt_weights<<<4 * 65536 / 256, 256, 0, stream>>>(Wq, Wk, Wv, Wproj, Wq_b, Wkv_b, Wp_b);

  const float scale = 0.04419417382415922f;  // 512^-0.5

  // q = proto @ Wq^T   rows flattened [8192][512]
  gemm_bt<0><<<dim3(4, 64, 1), 256, 0, stream>>>(
      proto_b, Wq_b, q_b, nullptr, DD, DD, DD, 0L, 0L, 0L, 0L,
      nullptr, nullptr, nullptr, 0.f, 0);
  // k | vT = qx @ [Wk;Wv]^T   rows flattened [32768][1024], dual epilogue
  gemm_bt<5><<<dim3(8, 256, 1), 256, 0, stream>>>(
      qx_b, Wkv_b, k_b, vT_b, 1024, DD, DD, 0L, 0L, 0L, 0L,
      nullptr, nullptr, nullptr, 0.f, 0);
  // P = exp(scale * q @ k^T) * mask ; denom += row sums
  gemm_bt<2><<<dim3(NKV / 128, NQ / 128, NB), 256, 0, stream>>>(
      q_b, k_b, P, nullptr, NKV, DD, DD, 0L,
      (long)NQ * DD, (long)NKV * DD, (long)NQ * NKV,
      mask, flag, denom, scale, NQ);
  // partials[chunk] = P[:, chunk] @ vT[:, chunk]^T   split-K 2-way, fp32
  gemm_bt<4><<<dim3(4, 8, 16), 256, 0, stream>>>(
      P, vT_b, part, nullptr, DD, NKV / 2, NKV, (long)NKV / 2,
      (long)NQ * NKV, (long)DD * NKV, (long)NQ * DD,
      nullptr, nullptr, nullptr, 0.f, 0);
  // x = (p0 + p1) / denom  -> bf16
  reduce_pv<<<NB * NQ * DD / 4 / 256, 256, 0, stream>>>(
      (const float4*)part, (const float4*)(part + (size_t)NB * NQ * DD),
      denom, (bf16x4*)x_b, NB * NQ * DD / 4);
  // out = x @ Wproj^T  fp32, rows flattened [8192][512]
  gemm_bt<4><<<dim3(4, 64, 1), 256, 0, stream>>>(
      x_b, Wp_b, out, nullptr, DD, DD, DD, 0L, 0L, 0L, 0L,
      nullptr, nullptr, nullptr, 0.f, 0);
}